// Round 1
// baseline (25377.361 us; speedup 1.0000x reference)
//
#include <hip/hip_runtime.h>

#define NU     200000
#define NNODES 600000
#define NE     10000000
#define DIM    64
#define BATCH  4096
#define KNEG   4
#define NSLOTS (BATCH * (2 + KNEG))

// ---------------------------------------------------------------------------
// Edge-parallel scatter SpMM: y[row[e]] += val[e] * x[col[e]]
// 16 threads per edge, each handles 4 dims (float4 gather + 4 f32 atomics).
// ---------------------------------------------------------------------------
__global__ __launch_bounds__(256) void spmm_kernel(
    const float* __restrict__ x, float* __restrict__ y,
    const float* __restrict__ val, const int* __restrict__ row,
    const int* __restrict__ col) {
  int t = blockIdx.x * 256 + threadIdx.x;
  int e = t >> 4;
  if (e >= NE) return;
  int sub = (t & 15) << 2;          // dim offset 0,4,...,60
  int r = row[e];
  int c = col[e];
  float v = val[e];
  float4 xv = *reinterpret_cast<const float4*>(x + (size_t)c * DIM + sub);
  float* yp = y + (size_t)r * DIM + sub;
  atomicAdd(yp + 0, v * xv.x);
  atomicAdd(yp + 1, v * xv.y);
  atomicAdd(yp + 2, v * xv.z);
  atomicAdd(yp + 3, v * xv.w);
}

// ---------------------------------------------------------------------------
// Accumulate x at the batch's needed rows into small per-slot buffers.
// Slot order: [0,B) user, [B,2B) pos, [2B, 2B+B*K) neg (flattened row-major).
// ---------------------------------------------------------------------------
__global__ __launch_bounds__(256) void gather_acc_kernel(
    const float* __restrict__ x,
    float* __restrict__ accU, float* __restrict__ accP, float* __restrict__ accN,
    const int* __restrict__ user, const int* __restrict__ pos,
    const int* __restrict__ neg) {
  int t = blockIdx.x * 256 + threadIdx.x;
  int slot = t >> 4;
  if (slot >= NSLOTS) return;
  int sub = (t & 15) << 2;
  const float* src;
  float* dst;
  if (slot < BATCH) {
    int n = user[slot];
    src = x + (size_t)n * DIM;
    dst = accU + (size_t)slot * DIM;
  } else if (slot < 2 * BATCH) {
    int b = slot - BATCH;
    int n = NU + pos[b];
    src = x + (size_t)n * DIM;
    dst = accP + (size_t)b * DIM;
  } else {
    int j = slot - 2 * BATCH;
    int n = NU + neg[j];
    src = x + (size_t)n * DIM;
    dst = accN + (size_t)j * DIM;
  }
  float4 s = *reinterpret_cast<const float4*>(src + sub);
  float4* d = reinterpret_cast<float4*>(dst + sub);
  float4 cur = *d;
  cur.x += s.x; cur.y += s.y; cur.z += s.z; cur.w += s.w;
  *d = cur;
}

// ---------------------------------------------------------------------------
// One wave (64 lanes) per batch sample; lane = dim. Butterfly reduce the
// BPR score diff and the L2 regularizer; one atomicAdd per wave per sum.
// ---------------------------------------------------------------------------
__global__ __launch_bounds__(256) void loss_kernel(
    const float* __restrict__ accU, const float* __restrict__ accP,
    const float* __restrict__ accN, const float* __restrict__ all_embed,
    const int* __restrict__ user, const int* __restrict__ pos,
    const int* __restrict__ neg, float* __restrict__ partial) {
  int gt = blockIdx.x * 256 + threadIdx.x;
  int b = gt >> 6;
  if (b >= BATCH) return;
  int lane = threadIdx.x & 63;

  float u = accU[(size_t)b * DIM + lane];
  float diff = u * accP[(size_t)b * DIM + lane];
  float nsum = 0.f;
  for (int k = 0; k < KNEG; ++k)
    nsum += u * accN[((size_t)b * KNEG + k) * DIM + lane];
  diff -= 0.25f * nsum;

  int un = user[b];
  int pn = NU + pos[b];
  float ue = all_embed[(size_t)un * DIM + lane];
  float pe = all_embed[(size_t)pn * DIM + lane];
  float reg = ue * ue + pe * pe;
  for (int k = 0; k < KNEG; ++k) {
    int nn = NU + neg[b * KNEG + k];
    float ne = all_embed[(size_t)nn * DIM + lane];
    reg += ne * ne;
  }

  for (int off = 1; off < 64; off <<= 1) {
    diff += __shfl_xor(diff, off);
    reg  += __shfl_xor(reg, off);
  }
  if (lane == 0) {
    float ls = (diff >= 0.f) ? -log1pf(expf(-diff))
                             : (diff - log1pf(expf(diff)));
    atomicAdd(partial + 0, -ls);   // sum of -log_sigmoid
    atomicAdd(partial + 1, reg);   // sum of squared embeddings
  }
}

__global__ void finalize_kernel(const float* __restrict__ partial,
                                float* __restrict__ out) {
  if (threadIdx.x == 0 && blockIdx.x == 0) {
    float mf  = partial[0] / (float)BATCH;
    float emb = 1e-4f * (partial[1] * 0.5f) / (float)BATCH;
    out[0] = mf + emb;
    out[1] = mf;
    out[2] = emb;
  }
}

// ---------------------------------------------------------------------------
extern "C" void kernel_launch(void* const* d_in, const int* in_sizes, int n_in,
                              void* d_out, int out_size, void* d_ws, size_t ws_size,
                              hipStream_t stream) {
  const float* all_embed = (const float*)d_in[0];
  const float* edge_val  = (const float*)d_in[1];
  const int*   edge_row  = (const int*)d_in[2];
  const int*   edge_col  = (const int*)d_in[3];
  const int*   user      = (const int*)d_in[4];
  const int*   pos       = (const int*)d_in[5];
  const int*   neg       = (const int*)d_in[6];
  float* out = (float*)d_out;

  // workspace layout (floats)
  float* bufA = (float*)d_ws;
  float* bufB = bufA + (size_t)NNODES * DIM;
  float* accU = bufB + (size_t)NNODES * DIM;
  float* accP = accU + (size_t)BATCH * DIM;
  float* accN = accP + (size_t)BATCH * DIM;
  float* partial = accN + (size_t)BATCH * KNEG * DIM;

  size_t nodeBytes = (size_t)NNODES * DIM * sizeof(float);
  size_t accBytes  = ((size_t)BATCH * DIM * 2 + (size_t)BATCH * KNEG * DIM + 2) *
                     sizeof(float);

  hipMemsetAsync(accU, 0, accBytes, stream);

  int gaBlocks = (NSLOTS * 16 + 255) / 256;
  int spBlocks = (int)(((size_t)NE * 16 + 255) / 256);
  int lsBlocks = (BATCH * 64 + 255) / 256;

  // hop 0: acc += all_embed[needed]
  gather_acc_kernel<<<gaBlocks, 256, 0, stream>>>(all_embed, accU, accP, accN,
                                                  user, pos, neg);
  // hop 1: bufA = A @ all_embed
  hipMemsetAsync(bufA, 0, nodeBytes, stream);
  spmm_kernel<<<spBlocks, 256, 0, stream>>>(all_embed, bufA, edge_val,
                                            edge_row, edge_col);
  gather_acc_kernel<<<gaBlocks, 256, 0, stream>>>(bufA, accU, accP, accN,
                                                  user, pos, neg);
  // hop 2: bufB = A @ bufA
  hipMemsetAsync(bufB, 0, nodeBytes, stream);
  spmm_kernel<<<spBlocks, 256, 0, stream>>>(bufA, bufB, edge_val,
                                            edge_row, edge_col);
  gather_acc_kernel<<<gaBlocks, 256, 0, stream>>>(bufB, accU, accP, accN,
                                                  user, pos, neg);
  // hop 3: bufA = A @ bufB  (bufA contents no longer needed)
  hipMemsetAsync(bufA, 0, nodeBytes, stream);
  spmm_kernel<<<spBlocks, 256, 0, stream>>>(bufB, bufA, edge_val,
                                            edge_row, edge_col);
  gather_acc_kernel<<<gaBlocks, 256, 0, stream>>>(bufA, accU, accP, accN,
                                                  user, pos, neg);

  loss_kernel<<<lsBlocks, 256, 0, stream>>>(accU, accP, accN, all_embed,
                                            user, pos, neg, partial);
  finalize_kernel<<<1, 64, 0, stream>>>(partial, out);
}

// Round 2
// 3243.744 us; speedup vs baseline: 7.8235x; 7.8235x over previous
//
#include <hip/hip_runtime.h>

#define NU     200000
#define NNODES 600000
#define NE     10000000
#define DIM    64
#define BATCH  4096
#define KNEG   4
#define NSLOTS (BATCH * (2 + KNEG))
#define SCAN_BLK 1024
#define NBLK1 ((NNODES + SCAN_BLK - 1) / SCAN_BLK)   // 586

// ---------------------------------------------------------------------------
// CSR construction: histogram -> exclusive scan -> scatter
// ---------------------------------------------------------------------------
__global__ __launch_bounds__(256) void hist_kernel(const int* __restrict__ row,
                                                   int* __restrict__ cnt) {
  int e = blockIdx.x * 256 + threadIdx.x;
  if (e < NE) atomicAdd(&cnt[row[e]], 1);
}

// Each block scans 1024 elements (4/thread); writes exclusive prefix + block sum.
__global__ __launch_bounds__(256) void scan1_kernel(const int* __restrict__ in,
                                                    int* __restrict__ out,
                                                    int* __restrict__ bsum) {
  __shared__ int lds[256];
  int tid = threadIdx.x;
  int base = blockIdx.x * SCAN_BLK + tid * 4;
  int a[4];
#pragma unroll
  for (int j = 0; j < 4; ++j) a[j] = (base + j < NNODES) ? in[base + j] : 0;
  int s = a[0] + a[1] + a[2] + a[3];
  lds[tid] = s;
  __syncthreads();
  for (int off = 1; off < 256; off <<= 1) {
    int v = (tid >= off) ? lds[tid - off] : 0;
    __syncthreads();
    lds[tid] += v;
    __syncthreads();
  }
  int excl = lds[tid] - s;
  if (tid == 255) bsum[blockIdx.x] = lds[255];
  int run = excl;
#pragma unroll
  for (int j = 0; j < 4; ++j) {
    if (base + j < NNODES) out[base + j] = run;
    run += a[j];
  }
}

__global__ __launch_bounds__(1024) void scan2_kernel(int* __restrict__ bsum, int n) {
  __shared__ int lds[1024];
  int tid = threadIdx.x;
  int x = (tid < n) ? bsum[tid] : 0;
  lds[tid] = x;
  __syncthreads();
  for (int off = 1; off < 1024; off <<= 1) {
    int v = (tid >= off) ? lds[tid - off] : 0;
    __syncthreads();
    lds[tid] += v;
    __syncthreads();
  }
  if (tid < n) bsum[tid] = lds[tid] - x;   // exclusive
}

__global__ __launch_bounds__(256) void scan3_kernel(int* __restrict__ out,
                                                    const int* __restrict__ bsum) {
  int i = blockIdx.x * 256 + threadIdx.x;
  if (i == 0) out[NNODES] = NE;
  if (i < NNODES) out[i] += bsum[i >> 10];
}

__global__ __launch_bounds__(256) void scatter_kernel(
    const int* __restrict__ row, const int* __restrict__ col,
    const float* __restrict__ val, int* __restrict__ cur,
    int* __restrict__ col_s, float* __restrict__ val_s) {
  int e = blockIdx.x * 256 + threadIdx.x;
  if (e >= NE) return;
  int p = atomicAdd(&cur[row[e]], 1);
  col_s[p] = col[e];
  val_s[p] = val[e];
}

// ---------------------------------------------------------------------------
// Pull-based SpMM: one wave per row, lane = dim. No atomics, one store/row.
// Rows with no edges write 0 (no memset needed).
// ---------------------------------------------------------------------------
__global__ __launch_bounds__(256) void spmm_pull_kernel(
    const float* __restrict__ x, float* __restrict__ y,
    const float* __restrict__ val_s, const int* __restrict__ col_s,
    const int* __restrict__ rowptr) {
  int w = (blockIdx.x * 256 + threadIdx.x) >> 6;
  if (w >= NNODES) return;
  int lane = threadIdx.x & 63;
  int beg = rowptr[w], end = rowptr[w + 1];
  float acc = 0.f;
  for (int i = beg; i < end; ++i) {
    float v = val_s[i];
    int c = col_s[i];
    acc = fmaf(v, x[(size_t)c * DIM + lane], acc);
  }
  y[(size_t)w * DIM + lane] = acc;
}

// Final hop: only compute the batch's rows, accumulate straight into acc.
__global__ __launch_bounds__(256) void slot_pull_kernel(
    const float* __restrict__ x,
    float* __restrict__ accU, float* __restrict__ accP, float* __restrict__ accN,
    const int* __restrict__ user, const int* __restrict__ pos,
    const int* __restrict__ neg,
    const float* __restrict__ val_s, const int* __restrict__ col_s,
    const int* __restrict__ rowptr) {
  int slot = (blockIdx.x * 256 + threadIdx.x) >> 6;
  if (slot >= NSLOTS) return;
  int lane = threadIdx.x & 63;
  int node;
  float* dst;
  if (slot < BATCH) {
    node = user[slot];
    dst = accU + (size_t)slot * DIM;
  } else if (slot < 2 * BATCH) {
    int b = slot - BATCH;
    node = NU + pos[b];
    dst = accP + (size_t)b * DIM;
  } else {
    int j = slot - 2 * BATCH;
    node = NU + neg[j];
    dst = accN + (size_t)j * DIM;
  }
  int beg = rowptr[node], end = rowptr[node + 1];
  float acc = 0.f;
  for (int i = beg; i < end; ++i)
    acc = fmaf(val_s[i], x[(size_t)col_s[i] * DIM + lane], acc);
  dst[lane] += acc;
}

// ---------------------------------------------------------------------------
// acc += x[batch rows] (hops 0..2)
// ---------------------------------------------------------------------------
__global__ __launch_bounds__(256) void gather_acc_kernel(
    const float* __restrict__ x,
    float* __restrict__ accU, float* __restrict__ accP, float* __restrict__ accN,
    const int* __restrict__ user, const int* __restrict__ pos,
    const int* __restrict__ neg) {
  int t = blockIdx.x * 256 + threadIdx.x;
  int slot = t >> 4;
  if (slot >= NSLOTS) return;
  int sub = (t & 15) << 2;
  const float* src;
  float* dst;
  if (slot < BATCH) {
    src = x + (size_t)user[slot] * DIM;
    dst = accU + (size_t)slot * DIM;
  } else if (slot < 2 * BATCH) {
    int b = slot - BATCH;
    src = x + (size_t)(NU + pos[b]) * DIM;
    dst = accP + (size_t)b * DIM;
  } else {
    int j = slot - 2 * BATCH;
    src = x + (size_t)(NU + neg[j]) * DIM;
    dst = accN + (size_t)j * DIM;
  }
  float4 s = *reinterpret_cast<const float4*>(src + sub);
  float4* d = reinterpret_cast<float4*>(dst + sub);
  float4 cur = *d;
  cur.x += s.x; cur.y += s.y; cur.z += s.z; cur.w += s.w;
  *d = cur;
}

// ---------------------------------------------------------------------------
// Loss: one wave per sample, butterfly reduce, one atomic per wave.
// ---------------------------------------------------------------------------
__global__ __launch_bounds__(256) void loss_kernel(
    const float* __restrict__ accU, const float* __restrict__ accP,
    const float* __restrict__ accN, const float* __restrict__ all_embed,
    const int* __restrict__ user, const int* __restrict__ pos,
    const int* __restrict__ neg, float* __restrict__ partial) {
  int gt = blockIdx.x * 256 + threadIdx.x;
  int b = gt >> 6;
  if (b >= BATCH) return;
  int lane = threadIdx.x & 63;

  float u = accU[(size_t)b * DIM + lane];
  float diff = u * accP[(size_t)b * DIM + lane];
  float nsum = 0.f;
  for (int k = 0; k < KNEG; ++k)
    nsum += u * accN[((size_t)b * KNEG + k) * DIM + lane];
  diff -= 0.25f * nsum;

  float ue = all_embed[(size_t)user[b] * DIM + lane];
  float pe = all_embed[(size_t)(NU + pos[b]) * DIM + lane];
  float reg = ue * ue + pe * pe;
  for (int k = 0; k < KNEG; ++k) {
    float ne = all_embed[(size_t)(NU + neg[b * KNEG + k]) * DIM + lane];
    reg += ne * ne;
  }

  for (int off = 1; off < 64; off <<= 1) {
    diff += __shfl_xor(diff, off);
    reg  += __shfl_xor(reg, off);
  }
  if (lane == 0) {
    float ls = (diff >= 0.f) ? -log1pf(expf(-diff))
                             : (diff - log1pf(expf(diff)));
    atomicAdd(partial + 0, -ls);
    atomicAdd(partial + 1, reg);
  }
}

__global__ void finalize_kernel(const float* __restrict__ partial,
                                float* __restrict__ out) {
  if (threadIdx.x == 0 && blockIdx.x == 0) {
    float mf  = partial[0] / (float)BATCH;
    float emb = 1e-4f * (partial[1] * 0.5f) / (float)BATCH;
    out[0] = mf + emb;
    out[1] = mf;
    out[2] = emb;
  }
}

// ---------------------------------------------------------------------------
extern "C" void kernel_launch(void* const* d_in, const int* in_sizes, int n_in,
                              void* d_out, int out_size, void* d_ws, size_t ws_size,
                              hipStream_t stream) {
  const float* all_embed = (const float*)d_in[0];
  const float* edge_val  = (const float*)d_in[1];
  const int*   edge_row  = (const int*)d_in[2];
  const int*   edge_col  = (const int*)d_in[3];
  const int*   user      = (const int*)d_in[4];
  const int*   pos       = (const int*)d_in[5];
  const int*   neg       = (const int*)d_in[6];
  float* out = (float*)d_out;

  // workspace layout (all 4-byte elements)
  int*   rowptr = (int*)d_ws;                  // NNODES+1
  int*   cur    = rowptr + (NNODES + 1);       // NNODES (also histogram)
  int*   bsum   = cur + NNODES;                // 1024
  int*   col_s  = bsum + 1024;                 // NE
  float* val_s  = (float*)(col_s + NE);        // NE
  float* bufA   = val_s + NE;                  // NNODES*DIM
  float* bufB   = bufA + (size_t)NNODES * DIM; // NNODES*DIM
  float* accU   = bufB + (size_t)NNODES * DIM;
  float* accP   = accU + (size_t)BATCH * DIM;
  float* accN   = accP + (size_t)BATCH * DIM;
  float* partial = accN + (size_t)BATCH * KNEG * DIM;

  size_t accBytes = ((size_t)BATCH * DIM * 2 + (size_t)BATCH * KNEG * DIM + 2) *
                    sizeof(float);

  int histBlocks = (NE + 255) / 256;
  int spBlocks   = (NNODES * 64 + 255) / 256;       // 150000
  int gaBlocks   = (NSLOTS * 16 + 255) / 256;
  int slBlocks   = (NSLOTS * 64 + 255) / 256;
  int lsBlocks   = (BATCH * 64 + 255) / 256;

  // --- build CSR ---
  hipMemsetAsync(cur, 0, NNODES * sizeof(int), stream);
  hipMemsetAsync(accU, 0, accBytes, stream);
  hist_kernel<<<histBlocks, 256, 0, stream>>>(edge_row, cur);
  scan1_kernel<<<NBLK1, 256, 0, stream>>>(cur, rowptr, bsum);
  scan2_kernel<<<1, 1024, 0, stream>>>(bsum, NBLK1);
  scan3_kernel<<<(NNODES + 255) / 256, 256, 0, stream>>>(rowptr, bsum);
  hipMemcpyAsync(cur, rowptr, NNODES * sizeof(int), hipMemcpyDeviceToDevice,
                 stream);
  scatter_kernel<<<histBlocks, 256, 0, stream>>>(edge_row, edge_col, edge_val,
                                                 cur, col_s, val_s);

  // --- hops ---
  gather_acc_kernel<<<gaBlocks, 256, 0, stream>>>(all_embed, accU, accP, accN,
                                                  user, pos, neg);
  spmm_pull_kernel<<<spBlocks, 256, 0, stream>>>(all_embed, bufA, val_s, col_s,
                                                 rowptr);
  gather_acc_kernel<<<gaBlocks, 256, 0, stream>>>(bufA, accU, accP, accN,
                                                  user, pos, neg);
  spmm_pull_kernel<<<spBlocks, 256, 0, stream>>>(bufA, bufB, val_s, col_s,
                                                 rowptr);
  gather_acc_kernel<<<gaBlocks, 256, 0, stream>>>(bufB, accU, accP, accN,
                                                  user, pos, neg);
  slot_pull_kernel<<<slBlocks, 256, 0, stream>>>(bufB, accU, accP, accN,
                                                 user, pos, neg, val_s, col_s,
                                                 rowptr);

  loss_kernel<<<lsBlocks, 256, 0, stream>>>(accU, accP, accN, all_embed,
                                            user, pos, neg, partial);
  finalize_kernel<<<1, 64, 0, stream>>>(partial, out);
}

// Round 3
// 1934.060 us; speedup vs baseline: 13.1213x; 1.6772x over previous
//
#include <hip/hip_runtime.h>

#define NU     200000
#define NNODES 600000
#define NE     10000000
#define DIM    64
#define BATCH  4096
#define KNEG   4
#define NSLOTS (BATCH * (2 + KNEG))
#define SCAN_BLK 1024
#define NBLK1 ((NNODES + SCAN_BLK - 1) / SCAN_BLK)   // 586

__device__ __forceinline__ float bf2f(unsigned short u) {
  return __uint_as_float(((unsigned int)u) << 16);
}
__device__ __forceinline__ unsigned short f2bf(float f) {   // RNE
  unsigned int x = __float_as_uint(f);
  return (unsigned short)((x + 0x7fffu + ((x >> 16) & 1u)) >> 16);
}

// ---------------------------------------------------------------------------
// f32 -> bf16 conversion of the embedding table
// ---------------------------------------------------------------------------
__global__ __launch_bounds__(256) void conv_kernel(
    const float* __restrict__ in, unsigned short* __restrict__ out) {
  size_t i = ((size_t)blockIdx.x * 256 + threadIdx.x) * 4;
  if (i >= (size_t)NNODES * DIM) return;
  float4 v = *reinterpret_cast<const float4*>(in + i);
  ushort4 o;
  o.x = f2bf(v.x); o.y = f2bf(v.y); o.z = f2bf(v.z); o.w = f2bf(v.w);
  *reinterpret_cast<ushort4*>(out + i) = o;
}

// ---------------------------------------------------------------------------
// CSR construction: histogram -> scan -> scatter (col+val fused into int2)
// ---------------------------------------------------------------------------
__global__ __launch_bounds__(256) void hist_kernel(const int* __restrict__ row,
                                                   int* __restrict__ cnt) {
  int base = (blockIdx.x * 256 + threadIdx.x) * 4;
  if (base + 4 <= NE) {
    int4 r = *reinterpret_cast<const int4*>(row + base);
    atomicAdd(&cnt[r.x], 1); atomicAdd(&cnt[r.y], 1);
    atomicAdd(&cnt[r.z], 1); atomicAdd(&cnt[r.w], 1);
  } else {
    for (int e = base; e < NE; ++e) atomicAdd(&cnt[row[e]], 1);
  }
}

__global__ __launch_bounds__(256) void scan1_kernel(const int* __restrict__ in,
                                                    int* __restrict__ out,
                                                    int* __restrict__ bsum) {
  __shared__ int lds[256];
  int tid = threadIdx.x;
  int base = blockIdx.x * SCAN_BLK + tid * 4;
  int a[4];
#pragma unroll
  for (int j = 0; j < 4; ++j) a[j] = (base + j < NNODES) ? in[base + j] : 0;
  int s = a[0] + a[1] + a[2] + a[3];
  lds[tid] = s;
  __syncthreads();
  for (int off = 1; off < 256; off <<= 1) {
    int v = (tid >= off) ? lds[tid - off] : 0;
    __syncthreads();
    lds[tid] += v;
    __syncthreads();
  }
  int excl = lds[tid] - s;
  if (tid == 255) bsum[blockIdx.x] = lds[255];
  int run = excl;
#pragma unroll
  for (int j = 0; j < 4; ++j) {
    if (base + j < NNODES) out[base + j] = run;
    run += a[j];
  }
}

__global__ __launch_bounds__(1024) void scan2_kernel(int* __restrict__ bsum, int n) {
  __shared__ int lds[1024];
  int tid = threadIdx.x;
  int x = (tid < n) ? bsum[tid] : 0;
  lds[tid] = x;
  __syncthreads();
  for (int off = 1; off < 1024; off <<= 1) {
    int v = (tid >= off) ? lds[tid - off] : 0;
    __syncthreads();
    lds[tid] += v;
    __syncthreads();
  }
  if (tid < n) bsum[tid] = lds[tid] - x;
}

// writes final rowptr AND seeds the scatter cursor (no d2d memcpy needed)
__global__ __launch_bounds__(256) void scan3_kernel(int* __restrict__ rowptr,
                                                    int* __restrict__ cur,
                                                    const int* __restrict__ bsum) {
  int i = blockIdx.x * 256 + threadIdx.x;
  if (i == 0) rowptr[NNODES] = NE;
  if (i < NNODES) {
    int v = rowptr[i] + bsum[i >> 10];
    rowptr[i] = v;
    cur[i] = v;
  }
}

__global__ __launch_bounds__(256) void scatter_kernel(
    const int* __restrict__ row, const int* __restrict__ col,
    const float* __restrict__ val, int* __restrict__ cur,
    int2* __restrict__ ev) {
  int e = blockIdx.x * 256 + threadIdx.x;
  if (e >= NE) return;
  int p = atomicAdd(&cur[row[e]], 1);
  int2 t;
  t.x = col[e];
  t.y = __float_as_int(val[e]);
  ev[p] = t;
}

// ---------------------------------------------------------------------------
// Mark rows needed from the LAST full SpMM: batch nodes + their edge cols.
// ---------------------------------------------------------------------------
__global__ __launch_bounds__(256) void mark_kernel(
    const int* __restrict__ user, const int* __restrict__ pos,
    const int* __restrict__ neg, const int* __restrict__ rowptr,
    const int2* __restrict__ ev, unsigned char* __restrict__ flag) {
  int s = blockIdx.x * 256 + threadIdx.x;
  if (s >= NSLOTS) return;
  int node;
  if (s < BATCH) node = user[s];
  else if (s < 2 * BATCH) node = NU + pos[s - BATCH];
  else node = NU + neg[s - 2 * BATCH];
  flag[node] = 1;
  int beg = rowptr[node], end = rowptr[node + 1];
  for (int i = beg; i < end; ++i) flag[ev[i].x] = 1;
}

// ---------------------------------------------------------------------------
// Pull SpMM, bf16 in / bf16 out, unroll-8 with 4 accumulators.
// ---------------------------------------------------------------------------
template <bool USE_FLAG>
__global__ __launch_bounds__(256) void spmm_pull_kernel(
    const unsigned short* __restrict__ x, unsigned short* __restrict__ y,
    const int2* __restrict__ ev, const int* __restrict__ rowptr,
    const unsigned char* __restrict__ flag) {
  int w = (blockIdx.x * 256 + threadIdx.x) >> 6;
  if (w >= NNODES) return;
  if (USE_FLAG && !flag[w]) return;
  int lane = threadIdx.x & 63;
  int beg = rowptr[w], end = rowptr[w + 1];
  float a0 = 0.f, a1 = 0.f, a2 = 0.f, a3 = 0.f;
  int i = beg;
  for (; i + 8 <= end; i += 8) {
    int2 e0 = ev[i],     e1 = ev[i + 1], e2 = ev[i + 2], e3 = ev[i + 3];
    int2 e4 = ev[i + 4], e5 = ev[i + 5], e6 = ev[i + 6], e7 = ev[i + 7];
    float x0 = bf2f(x[(size_t)e0.x * DIM + lane]);
    float x1 = bf2f(x[(size_t)e1.x * DIM + lane]);
    float x2 = bf2f(x[(size_t)e2.x * DIM + lane]);
    float x3 = bf2f(x[(size_t)e3.x * DIM + lane]);
    float x4 = bf2f(x[(size_t)e4.x * DIM + lane]);
    float x5 = bf2f(x[(size_t)e5.x * DIM + lane]);
    float x6 = bf2f(x[(size_t)e6.x * DIM + lane]);
    float x7 = bf2f(x[(size_t)e7.x * DIM + lane]);
    a0 = fmaf(__int_as_float(e0.y), x0, a0);
    a1 = fmaf(__int_as_float(e1.y), x1, a1);
    a2 = fmaf(__int_as_float(e2.y), x2, a2);
    a3 = fmaf(__int_as_float(e3.y), x3, a3);
    a0 = fmaf(__int_as_float(e4.y), x4, a0);
    a1 = fmaf(__int_as_float(e5.y), x5, a1);
    a2 = fmaf(__int_as_float(e6.y), x6, a2);
    a3 = fmaf(__int_as_float(e7.y), x7, a3);
  }
  for (; i < end; ++i) {
    int2 e = ev[i];
    a0 = fmaf(__int_as_float(e.y), bf2f(x[(size_t)e.x * DIM + lane]), a0);
  }
  y[(size_t)w * DIM + lane] = f2bf((a0 + a1) + (a2 + a3));
}

// ---------------------------------------------------------------------------
// Final hop: only the batch's rows, accumulate into acc (f32).
// ---------------------------------------------------------------------------
__global__ __launch_bounds__(256) void slot_pull_kernel(
    const unsigned short* __restrict__ x,
    float* __restrict__ accU, float* __restrict__ accP, float* __restrict__ accN,
    const int* __restrict__ user, const int* __restrict__ pos,
    const int* __restrict__ neg,
    const int2* __restrict__ ev, const int* __restrict__ rowptr) {
  int slot = (blockIdx.x * 256 + threadIdx.x) >> 6;
  if (slot >= NSLOTS) return;
  int lane = threadIdx.x & 63;
  int node;
  float* dst;
  if (slot < BATCH) {
    node = user[slot];
    dst = accU + (size_t)slot * DIM;
  } else if (slot < 2 * BATCH) {
    int b = slot - BATCH;
    node = NU + pos[b];
    dst = accP + (size_t)b * DIM;
  } else {
    int j = slot - 2 * BATCH;
    node = NU + neg[j];
    dst = accN + (size_t)j * DIM;
  }
  int beg = rowptr[node], end = rowptr[node + 1];
  float a0 = 0.f, a1 = 0.f, a2 = 0.f, a3 = 0.f;
  int i = beg;
  for (; i + 4 <= end; i += 4) {
    int2 e0 = ev[i], e1 = ev[i + 1], e2 = ev[i + 2], e3 = ev[i + 3];
    a0 = fmaf(__int_as_float(e0.y), bf2f(x[(size_t)e0.x * DIM + lane]), a0);
    a1 = fmaf(__int_as_float(e1.y), bf2f(x[(size_t)e1.x * DIM + lane]), a1);
    a2 = fmaf(__int_as_float(e2.y), bf2f(x[(size_t)e2.x * DIM + lane]), a2);
    a3 = fmaf(__int_as_float(e3.y), bf2f(x[(size_t)e3.x * DIM + lane]), a3);
  }
  for (; i < end; ++i) {
    int2 e = ev[i];
    a0 = fmaf(__int_as_float(e.y), bf2f(x[(size_t)e.x * DIM + lane]), a0);
  }
  dst[lane] += (a0 + a1) + (a2 + a3);
}

// ---------------------------------------------------------------------------
// acc += x[batch rows] — f32 source (hop 0)
// ---------------------------------------------------------------------------
__global__ __launch_bounds__(256) void gather_acc_f32(
    const float* __restrict__ x,
    float* __restrict__ accU, float* __restrict__ accP, float* __restrict__ accN,
    const int* __restrict__ user, const int* __restrict__ pos,
    const int* __restrict__ neg) {
  int t = blockIdx.x * 256 + threadIdx.x;
  int slot = t >> 4;
  if (slot >= NSLOTS) return;
  int sub = (t & 15) << 2;
  int node;
  float* dst;
  if (slot < BATCH) {
    node = user[slot];
    dst = accU + (size_t)slot * DIM;
  } else if (slot < 2 * BATCH) {
    int b = slot - BATCH;
    node = NU + pos[b];
    dst = accP + (size_t)b * DIM;
  } else {
    int j = slot - 2 * BATCH;
    node = NU + neg[j];
    dst = accN + (size_t)j * DIM;
  }
  float4 s = *reinterpret_cast<const float4*>(x + (size_t)node * DIM + sub);
  float4* d = reinterpret_cast<float4*>(dst + sub);
  float4 c = *d;
  c.x += s.x; c.y += s.y; c.z += s.z; c.w += s.w;
  *d = c;
}

// acc += x[batch rows] — bf16 source (hops 1,2)
__global__ __launch_bounds__(256) void gather_acc_bf16(
    const unsigned short* __restrict__ x,
    float* __restrict__ accU, float* __restrict__ accP, float* __restrict__ accN,
    const int* __restrict__ user, const int* __restrict__ pos,
    const int* __restrict__ neg) {
  int t = blockIdx.x * 256 + threadIdx.x;
  int slot = t >> 4;
  if (slot >= NSLOTS) return;
  int sub = (t & 15) << 2;
  int node;
  float* dst;
  if (slot < BATCH) {
    node = user[slot];
    dst = accU + (size_t)slot * DIM;
  } else if (slot < 2 * BATCH) {
    int b = slot - BATCH;
    node = NU + pos[b];
    dst = accP + (size_t)b * DIM;
  } else {
    int j = slot - 2 * BATCH;
    node = NU + neg[j];
    dst = accN + (size_t)j * DIM;
  }
  ushort4 s = *reinterpret_cast<const ushort4*>(x + (size_t)node * DIM + sub);
  float4* d = reinterpret_cast<float4*>(dst + sub);
  float4 c = *d;
  c.x += bf2f(s.x); c.y += bf2f(s.y); c.z += bf2f(s.z); c.w += bf2f(s.w);
  *d = c;
}

// ---------------------------------------------------------------------------
// Loss
// ---------------------------------------------------------------------------
__global__ __launch_bounds__(256) void loss_kernel(
    const float* __restrict__ accU, const float* __restrict__ accP,
    const float* __restrict__ accN, const float* __restrict__ all_embed,
    const int* __restrict__ user, const int* __restrict__ pos,
    const int* __restrict__ neg, float* __restrict__ partial) {
  int gt = blockIdx.x * 256 + threadIdx.x;
  int b = gt >> 6;
  if (b >= BATCH) return;
  int lane = threadIdx.x & 63;

  float u = accU[(size_t)b * DIM + lane];
  float diff = u * accP[(size_t)b * DIM + lane];
  float nsum = 0.f;
  for (int k = 0; k < KNEG; ++k)
    nsum += u * accN[((size_t)b * KNEG + k) * DIM + lane];
  diff -= 0.25f * nsum;

  float ue = all_embed[(size_t)user[b] * DIM + lane];
  float pe = all_embed[(size_t)(NU + pos[b]) * DIM + lane];
  float reg = ue * ue + pe * pe;
  for (int k = 0; k < KNEG; ++k) {
    float ne = all_embed[(size_t)(NU + neg[b * KNEG + k]) * DIM + lane];
    reg += ne * ne;
  }

  for (int off = 1; off < 64; off <<= 1) {
    diff += __shfl_xor(diff, off);
    reg  += __shfl_xor(reg, off);
  }
  if (lane == 0) {
    float ls = (diff >= 0.f) ? -log1pf(expf(-diff))
                             : (diff - log1pf(expf(diff)));
    atomicAdd(partial + 0, -ls);
    atomicAdd(partial + 1, reg);
  }
}

__global__ void finalize_kernel(const float* __restrict__ partial,
                                float* __restrict__ out) {
  if (threadIdx.x == 0 && blockIdx.x == 0) {
    float mf  = partial[0] / (float)BATCH;
    float emb = 1e-4f * (partial[1] * 0.5f) / (float)BATCH;
    out[0] = mf + emb;
    out[1] = mf;
    out[2] = emb;
  }
}

// ---------------------------------------------------------------------------
extern "C" void kernel_launch(void* const* d_in, const int* in_sizes, int n_in,
                              void* d_out, int out_size, void* d_ws, size_t ws_size,
                              hipStream_t stream) {
  const float* all_embed = (const float*)d_in[0];
  const float* edge_val  = (const float*)d_in[1];
  const int*   edge_row  = (const int*)d_in[2];
  const int*   edge_col  = (const int*)d_in[3];
  const int*   user      = (const int*)d_in[4];
  const int*   pos       = (const int*)d_in[5];
  const int*   neg       = (const int*)d_in[6];
  float* out = (float*)d_out;

  // workspace layout (ev first for 8B alignment)
  char* base = (char*)d_ws;
  size_t off = 0;
  int2* ev = (int2*)(base + off);            off += (size_t)NE * 8;
  int* rowptr = (int*)(base + off);          off += (size_t)(NNODES + 1) * 4;
  int* cur    = (int*)(base + off);          off += (size_t)NNODES * 4;
  int* bsum   = (int*)(base + off);          off += 1024 * 4;
  off = (off + 255) & ~(size_t)255;
  unsigned char* flag = (unsigned char*)(base + off); off += NNODES;
  off = (off + 255) & ~(size_t)255;
  unsigned short* xb0  = (unsigned short*)(base + off); off += (size_t)NNODES * DIM * 2;
  unsigned short* bufA = (unsigned short*)(base + off); off += (size_t)NNODES * DIM * 2;
  unsigned short* bufB = (unsigned short*)(base + off); off += (size_t)NNODES * DIM * 2;
  off = (off + 255) & ~(size_t)255;
  float* accU = (float*)(base + off);        off += (size_t)BATCH * DIM * 4;
  float* accP = (float*)(base + off);        off += (size_t)BATCH * DIM * 4;
  float* accN = (float*)(base + off);        off += (size_t)BATCH * KNEG * DIM * 4;
  float* partial = (float*)(base + off);

  size_t accBytes = ((size_t)BATCH * DIM * 2 + (size_t)BATCH * KNEG * DIM + 2) *
                    sizeof(float);

  int convBlocks = (int)(((size_t)NNODES * DIM / 4 + 255) / 256);
  int histBlocks = (NE / 4 + 255) / 256;
  int scatBlocks = (NE + 255) / 256;
  int spBlocks   = (NNODES * 64 + 255) / 256;
  int gaBlocks   = (NSLOTS * 16 + 255) / 256;
  int slBlocks   = (NSLOTS * 64 + 255) / 256;
  int mkBlocks   = (NSLOTS + 255) / 256;
  int lsBlocks   = (BATCH * 64 + 255) / 256;

  hipMemsetAsync(cur, 0, (size_t)NNODES * 4, stream);
  hipMemsetAsync(flag, 0, NNODES, stream);
  hipMemsetAsync(accU, 0, accBytes, stream);

  conv_kernel<<<convBlocks, 256, 0, stream>>>(all_embed, xb0);
  hist_kernel<<<histBlocks, 256, 0, stream>>>(edge_row, cur);
  scan1_kernel<<<NBLK1, 256, 0, stream>>>(cur, rowptr, bsum);
  scan2_kernel<<<1, 1024, 0, stream>>>(bsum, NBLK1);
  scan3_kernel<<<(NNODES + 255) / 256, 256, 0, stream>>>(rowptr, cur, bsum);
  scatter_kernel<<<scatBlocks, 256, 0, stream>>>(edge_row, edge_col, edge_val,
                                                 cur, ev);
  mark_kernel<<<mkBlocks, 256, 0, stream>>>(user, pos, neg, rowptr, ev, flag);

  // hop 0
  gather_acc_f32<<<gaBlocks, 256, 0, stream>>>(all_embed, accU, accP, accN,
                                               user, pos, neg);
  // hop 1 (all rows)
  spmm_pull_kernel<false><<<spBlocks, 256, 0, stream>>>(xb0, bufA, ev, rowptr,
                                                        flag);
  gather_acc_bf16<<<gaBlocks, 256, 0, stream>>>(bufA, accU, accP, accN,
                                                user, pos, neg);
  // hop 2 (flagged rows only)
  spmm_pull_kernel<true><<<spBlocks, 256, 0, stream>>>(bufA, bufB, ev, rowptr,
                                                       flag);
  gather_acc_bf16<<<gaBlocks, 256, 0, stream>>>(bufB, accU, accP, accN,
                                                user, pos, neg);
  // hop 3 (batch rows only)
  slot_pull_kernel<<<slBlocks, 256, 0, stream>>>(bufB, accU, accP, accN,
                                                 user, pos, neg, ev, rowptr);

  loss_kernel<<<lsBlocks, 256, 0, stream>>>(accU, accP, accN, all_embed,
                                            user, pos, neg, partial);
  finalize_kernel<<<1, 64, 0, stream>>>(partial, out);
}

// Round 4
// 1921.659 us; speedup vs baseline: 13.2060x; 1.0065x over previous
//
#include <hip/hip_runtime.h>

#define NU     200000
#define NNODES 600000
#define NE     10000000
#define DIM    64
#define BATCH  4096
#define KNEG   4
#define NSLOTS (BATCH * (2 + KNEG))
#define SCAN_BLK 1024
#define NBLK1 ((NNODES + SCAN_BLK - 1) / SCAN_BLK)   // 586
#define BSHIFT 7
#define BROWS  128
#define NBUCK  ((NNODES + BROWS - 1) / BROWS)        // 4688

__device__ __forceinline__ float bf2f(unsigned short u) {
  return __uint_as_float(((unsigned int)u) << 16);
}
__device__ __forceinline__ unsigned short f2bf(float f) {   // RNE
  unsigned int x = __float_as_uint(f);
  return (unsigned short)((x + 0x7fffu + ((x >> 16) & 1u)) >> 16);
}

// ---------------------------------------------------------------------------
// f32 -> bf16 conversion of the embedding table
// ---------------------------------------------------------------------------
__global__ __launch_bounds__(256) void conv_kernel(
    const float* __restrict__ in, unsigned short* __restrict__ out) {
  size_t i = ((size_t)blockIdx.x * 256 + threadIdx.x) * 4;
  if (i >= (size_t)NNODES * DIM) return;
  float4 v = *reinterpret_cast<const float4*>(in + i);
  ushort4 o;
  o.x = f2bf(v.x); o.y = f2bf(v.y); o.z = f2bf(v.z); o.w = f2bf(v.w);
  *reinterpret_cast<ushort4*>(out + i) = o;
}

// ---------------------------------------------------------------------------
// CSR construction: histogram -> scan -> bucket-binning (binA) -> fine (binB)
// ---------------------------------------------------------------------------
__global__ __launch_bounds__(256) void hist_kernel(const int* __restrict__ row,
                                                   int* __restrict__ cnt) {
  int base = (blockIdx.x * 256 + threadIdx.x) * 4;
  if (base + 4 <= NE) {
    int4 r = *reinterpret_cast<const int4*>(row + base);
    atomicAdd(&cnt[r.x], 1); atomicAdd(&cnt[r.y], 1);
    atomicAdd(&cnt[r.z], 1); atomicAdd(&cnt[r.w], 1);
  } else {
    for (int e = base; e < NE; ++e) atomicAdd(&cnt[row[e]], 1);
  }
}

__global__ __launch_bounds__(256) void scan1_kernel(const int* __restrict__ in,
                                                    int* __restrict__ out,
                                                    int* __restrict__ bsum) {
  __shared__ int lds[256];
  int tid = threadIdx.x;
  int base = blockIdx.x * SCAN_BLK + tid * 4;
  int a[4];
#pragma unroll
  for (int j = 0; j < 4; ++j) a[j] = (base + j < NNODES) ? in[base + j] : 0;
  int s = a[0] + a[1] + a[2] + a[3];
  lds[tid] = s;
  __syncthreads();
  for (int off = 1; off < 256; off <<= 1) {
    int v = (tid >= off) ? lds[tid - off] : 0;
    __syncthreads();
    lds[tid] += v;
    __syncthreads();
  }
  int excl = lds[tid] - s;
  if (tid == 255) bsum[blockIdx.x] = lds[255];
  int run = excl;
#pragma unroll
  for (int j = 0; j < 4; ++j) {
    if (base + j < NNODES) out[base + j] = run;
    run += a[j];
  }
}

__global__ __launch_bounds__(1024) void scan2_kernel(int* __restrict__ bsum, int n) {
  __shared__ int lds[1024];
  int tid = threadIdx.x;
  int x = (tid < n) ? bsum[tid] : 0;
  lds[tid] = x;
  __syncthreads();
  for (int off = 1; off < 1024; off <<= 1) {
    int v = (tid >= off) ? lds[tid - off] : 0;
    __syncthreads();
    lds[tid] += v;
    __syncthreads();
  }
  if (tid < n) bsum[tid] = lds[tid] - x;
}

__global__ __launch_bounds__(256) void scan3_kernel(int* __restrict__ rowptr,
                                                    const int* __restrict__ bsum) {
  int i = blockIdx.x * 256 + threadIdx.x;
  if (i == 0) rowptr[NNODES] = NE;
  if (i < NNODES) rowptr[i] += bsum[i >> 10];
}

// seed bucket cursors from rowptr (bucket regions are contiguous in CSR)
__global__ __launch_bounds__(256) void seed_kernel(int* __restrict__ bcur,
                                                   const int* __restrict__ rowptr) {
  int b = blockIdx.x * 256 + threadIdx.x;
  if (b < NBUCK) bcur[b] = rowptr[b << BSHIFT];
}

// coarse scatter: edges -> 128-row bucket regions (frontier-local stores)
__global__ __launch_bounds__(256) void binA_kernel(
    const int* __restrict__ row, const int* __restrict__ col,
    const float* __restrict__ val, int* __restrict__ bcur,
    int2* __restrict__ binned) {
  int e = blockIdx.x * 256 + threadIdx.x;
  if (e >= NE) return;
  int r = row[e];
  int p = atomicAdd(&bcur[r >> BSHIFT], 1);
  int2 t;
  t.x = col[e] | ((r & (BROWS - 1)) << 20);   // col < 2^20
  t.y = __float_as_int(val[e]);
  binned[p] = t;
}

// fine placement within bucket: LDS cursors, 17KB L2-hit store window
__global__ __launch_bounds__(512) void binB_kernel(
    const int2* __restrict__ binned, const int* __restrict__ rowptr,
    int2* __restrict__ ev) {
  __shared__ int cur[BROWS];
  int b = blockIdx.x;
  int base = b << BSHIFT;
  int tid = threadIdx.x;
  if (tid < BROWS) {
    int rr = base + tid;
    cur[tid] = (rr < NNODES) ? rowptr[rr] : NE;
  }
  int beg = rowptr[base];
  int endi = base + BROWS;
  int end = rowptr[endi < NNODES ? endi : NNODES];
  __syncthreads();
  for (int i = beg + tid; i < end; i += 512) {
    int2 t = binned[i];
    int rlow = (t.x >> 20) & (BROWS - 1);
    int p = atomicAdd(&cur[rlow], 1);
    int2 o;
    o.x = t.x & 0xFFFFF;
    o.y = t.y;
    ev[p] = o;
  }
}

// ---------------------------------------------------------------------------
// Mark rows needed from the LAST full SpMM: batch nodes + their edge cols.
// ---------------------------------------------------------------------------
__global__ __launch_bounds__(256) void mark_kernel(
    const int* __restrict__ user, const int* __restrict__ pos,
    const int* __restrict__ neg, const int* __restrict__ rowptr,
    const int2* __restrict__ ev, unsigned char* __restrict__ flag) {
  int s = blockIdx.x * 256 + threadIdx.x;
  if (s >= NSLOTS) return;
  int node;
  if (s < BATCH) node = user[s];
  else if (s < 2 * BATCH) node = NU + pos[s - BATCH];
  else node = NU + neg[s - 2 * BATCH];
  flag[node] = 1;
  int beg = rowptr[node], end = rowptr[node + 1];
  for (int i = beg; i < end; ++i) flag[ev[i].x] = 1;
}

// ---------------------------------------------------------------------------
// Pull SpMM, bf16 in / bf16 out, unroll-8 with 4 accumulators.
// ---------------------------------------------------------------------------
template <bool USE_FLAG>
__global__ __launch_bounds__(256) void spmm_pull_kernel(
    const unsigned short* __restrict__ x, unsigned short* __restrict__ y,
    const int2* __restrict__ ev, const int* __restrict__ rowptr,
    const unsigned char* __restrict__ flag) {
  int w = (blockIdx.x * 256 + threadIdx.x) >> 6;
  if (w >= NNODES) return;
  if (USE_FLAG && !flag[w]) return;
  int lane = threadIdx.x & 63;
  int beg = rowptr[w], end = rowptr[w + 1];
  float a0 = 0.f, a1 = 0.f, a2 = 0.f, a3 = 0.f;
  int i = beg;
  for (; i + 8 <= end; i += 8) {
    int2 e0 = ev[i],     e1 = ev[i + 1], e2 = ev[i + 2], e3 = ev[i + 3];
    int2 e4 = ev[i + 4], e5 = ev[i + 5], e6 = ev[i + 6], e7 = ev[i + 7];
    float x0 = bf2f(x[(size_t)e0.x * DIM + lane]);
    float x1 = bf2f(x[(size_t)e1.x * DIM + lane]);
    float x2 = bf2f(x[(size_t)e2.x * DIM + lane]);
    float x3 = bf2f(x[(size_t)e3.x * DIM + lane]);
    float x4 = bf2f(x[(size_t)e4.x * DIM + lane]);
    float x5 = bf2f(x[(size_t)e5.x * DIM + lane]);
    float x6 = bf2f(x[(size_t)e6.x * DIM + lane]);
    float x7 = bf2f(x[(size_t)e7.x * DIM + lane]);
    a0 = fmaf(__int_as_float(e0.y), x0, a0);
    a1 = fmaf(__int_as_float(e1.y), x1, a1);
    a2 = fmaf(__int_as_float(e2.y), x2, a2);
    a3 = fmaf(__int_as_float(e3.y), x3, a3);
    a0 = fmaf(__int_as_float(e4.y), x4, a0);
    a1 = fmaf(__int_as_float(e5.y), x5, a1);
    a2 = fmaf(__int_as_float(e6.y), x6, a2);
    a3 = fmaf(__int_as_float(e7.y), x7, a3);
  }
  for (; i < end; ++i) {
    int2 e = ev[i];
    a0 = fmaf(__int_as_float(e.y), bf2f(x[(size_t)e.x * DIM + lane]), a0);
  }
  y[(size_t)w * DIM + lane] = f2bf((a0 + a1) + (a2 + a3));
}

// ---------------------------------------------------------------------------
// Final hop: only the batch's rows, accumulate into acc (f32).
// ---------------------------------------------------------------------------
__global__ __launch_bounds__(256) void slot_pull_kernel(
    const unsigned short* __restrict__ x,
    float* __restrict__ accU, float* __restrict__ accP, float* __restrict__ accN,
    const int* __restrict__ user, const int* __restrict__ pos,
    const int* __restrict__ neg,
    const int2* __restrict__ ev, const int* __restrict__ rowptr) {
  int slot = (blockIdx.x * 256 + threadIdx.x) >> 6;
  if (slot >= NSLOTS) return;
  int lane = threadIdx.x & 63;
  int node;
  float* dst;
  if (slot < BATCH) {
    node = user[slot];
    dst = accU + (size_t)slot * DIM;
  } else if (slot < 2 * BATCH) {
    int b = slot - BATCH;
    node = NU + pos[b];
    dst = accP + (size_t)b * DIM;
  } else {
    int j = slot - 2 * BATCH;
    node = NU + neg[j];
    dst = accN + (size_t)j * DIM;
  }
  int beg = rowptr[node], end = rowptr[node + 1];
  float a0 = 0.f, a1 = 0.f, a2 = 0.f, a3 = 0.f;
  int i = beg;
  for (; i + 4 <= end; i += 4) {
    int2 e0 = ev[i], e1 = ev[i + 1], e2 = ev[i + 2], e3 = ev[i + 3];
    a0 = fmaf(__int_as_float(e0.y), bf2f(x[(size_t)e0.x * DIM + lane]), a0);
    a1 = fmaf(__int_as_float(e1.y), bf2f(x[(size_t)e1.x * DIM + lane]), a1);
    a2 = fmaf(__int_as_float(e2.y), bf2f(x[(size_t)e2.x * DIM + lane]), a2);
    a3 = fmaf(__int_as_float(e3.y), bf2f(x[(size_t)e3.x * DIM + lane]), a3);
  }
  for (; i < end; ++i) {
    int2 e = ev[i];
    a0 = fmaf(__int_as_float(e.y), bf2f(x[(size_t)e.x * DIM + lane]), a0);
  }
  dst[lane] += (a0 + a1) + (a2 + a3);
}

// ---------------------------------------------------------------------------
// acc += x[batch rows] — f32 source (hop 0)
// ---------------------------------------------------------------------------
__global__ __launch_bounds__(256) void gather_acc_f32(
    const float* __restrict__ x,
    float* __restrict__ accU, float* __restrict__ accP, float* __restrict__ accN,
    const int* __restrict__ user, const int* __restrict__ pos,
    const int* __restrict__ neg) {
  int t = blockIdx.x * 256 + threadIdx.x;
  int slot = t >> 4;
  if (slot >= NSLOTS) return;
  int sub = (t & 15) << 2;
  int node;
  float* dst;
  if (slot < BATCH) {
    node = user[slot];
    dst = accU + (size_t)slot * DIM;
  } else if (slot < 2 * BATCH) {
    int b = slot - BATCH;
    node = NU + pos[b];
    dst = accP + (size_t)b * DIM;
  } else {
    int j = slot - 2 * BATCH;
    node = NU + neg[j];
    dst = accN + (size_t)j * DIM;
  }
  float4 s = *reinterpret_cast<const float4*>(x + (size_t)node * DIM + sub);
  float4* d = reinterpret_cast<float4*>(dst + sub);
  float4 c = *d;
  c.x += s.x; c.y += s.y; c.z += s.z; c.w += s.w;
  *d = c;
}

// acc += x[batch rows] — bf16 source (hops 1,2)
__global__ __launch_bounds__(256) void gather_acc_bf16(
    const unsigned short* __restrict__ x,
    float* __restrict__ accU, float* __restrict__ accP, float* __restrict__ accN,
    const int* __restrict__ user, const int* __restrict__ pos,
    const int* __restrict__ neg) {
  int t = blockIdx.x * 256 + threadIdx.x;
  int slot = t >> 4;
  if (slot >= NSLOTS) return;
  int sub = (t & 15) << 2;
  int node;
  float* dst;
  if (slot < BATCH) {
    node = user[slot];
    dst = accU + (size_t)slot * DIM;
  } else if (slot < 2 * BATCH) {
    int b = slot - BATCH;
    node = NU + pos[b];
    dst = accP + (size_t)b * DIM;
  } else {
    int j = slot - 2 * BATCH;
    node = NU + neg[j];
    dst = accN + (size_t)j * DIM;
  }
  ushort4 s = *reinterpret_cast<const ushort4*>(x + (size_t)node * DIM + sub);
  float4* d = reinterpret_cast<float4*>(dst + sub);
  float4 c = *d;
  c.x += bf2f(s.x); c.y += bf2f(s.y); c.z += bf2f(s.z); c.w += bf2f(s.w);
  *d = c;
}

// ---------------------------------------------------------------------------
// Loss
// ---------------------------------------------------------------------------
__global__ __launch_bounds__(256) void loss_kernel(
    const float* __restrict__ accU, const float* __restrict__ accP,
    const float* __restrict__ accN, const float* __restrict__ all_embed,
    const int* __restrict__ user, const int* __restrict__ pos,
    const int* __restrict__ neg, float* __restrict__ partial) {
  int gt = blockIdx.x * 256 + threadIdx.x;
  int b = gt >> 6;
  if (b >= BATCH) return;
  int lane = threadIdx.x & 63;

  float u = accU[(size_t)b * DIM + lane];
  float diff = u * accP[(size_t)b * DIM + lane];
  float nsum = 0.f;
  for (int k = 0; k < KNEG; ++k)
    nsum += u * accN[((size_t)b * KNEG + k) * DIM + lane];
  diff -= 0.25f * nsum;

  float ue = all_embed[(size_t)user[b] * DIM + lane];
  float pe = all_embed[(size_t)(NU + pos[b]) * DIM + lane];
  float reg = ue * ue + pe * pe;
  for (int k = 0; k < KNEG; ++k) {
    float ne = all_embed[(size_t)(NU + neg[b * KNEG + k]) * DIM + lane];
    reg += ne * ne;
  }

  for (int off = 1; off < 64; off <<= 1) {
    diff += __shfl_xor(diff, off);
    reg  += __shfl_xor(reg, off);
  }
  if (lane == 0) {
    float ls = (diff >= 0.f) ? -log1pf(expf(-diff))
                             : (diff - log1pf(expf(diff)));
    atomicAdd(partial + 0, -ls);
    atomicAdd(partial + 1, reg);
  }
}

__global__ void finalize_kernel(const float* __restrict__ partial,
                                float* __restrict__ out) {
  if (threadIdx.x == 0 && blockIdx.x == 0) {
    float mf  = partial[0] / (float)BATCH;
    float emb = 1e-4f * (partial[1] * 0.5f) / (float)BATCH;
    out[0] = mf + emb;
    out[1] = mf;
    out[2] = emb;
  }
}

// ---------------------------------------------------------------------------
extern "C" void kernel_launch(void* const* d_in, const int* in_sizes, int n_in,
                              void* d_out, int out_size, void* d_ws, size_t ws_size,
                              hipStream_t stream) {
  const float* all_embed = (const float*)d_in[0];
  const float* edge_val  = (const float*)d_in[1];
  const int*   edge_row  = (const int*)d_in[2];
  const int*   edge_col  = (const int*)d_in[3];
  const int*   user      = (const int*)d_in[4];
  const int*   pos       = (const int*)d_in[5];
  const int*   neg       = (const int*)d_in[6];
  float* out = (float*)d_out;

  // workspace layout
  char* base = (char*)d_ws;
  size_t off = 0;
  int2* ev = (int2*)(base + off);            off += (size_t)NE * 8;
  int* rowptr = (int*)(base + off);          off += (size_t)(NNODES + 1) * 4;
  int* cnt    = (int*)(base + off);          off += (size_t)NNODES * 4;
  int* bsum   = (int*)(base + off);          off += 1024 * 4;
  int* bcur   = (int*)(base + off);          off += (size_t)NBUCK * 4;
  off = (off + 255) & ~(size_t)255;
  unsigned char* flag = (unsigned char*)(base + off); off += NNODES;
  off = (off + 255) & ~(size_t)255;
  unsigned short* xb0  = (unsigned short*)(base + off); off += (size_t)NNODES * DIM * 2;
  unsigned short* bufA = (unsigned short*)(base + off); off += (size_t)NNODES * DIM * 2;
  unsigned short* bufB = (unsigned short*)(base + off); off += (size_t)NNODES * DIM * 2;
  off = (off + 255) & ~(size_t)255;
  float* accU = (float*)(base + off);        off += (size_t)BATCH * DIM * 4;
  float* accP = (float*)(base + off);        off += (size_t)BATCH * DIM * 4;
  float* accN = (float*)(base + off);        off += (size_t)BATCH * KNEG * DIM * 4;
  float* partial = (float*)(base + off);

  // binned aliases bufA(+start of bufB): dead before hop 1 writes bufA
  int2* binned = (int2*)bufA;

  size_t accBytes = ((size_t)BATCH * DIM * 2 + (size_t)BATCH * KNEG * DIM + 2) *
                    sizeof(float);

  int convBlocks = (int)(((size_t)NNODES * DIM / 4 + 255) / 256);
  int histBlocks = (NE / 4 + 255) / 256;
  int edgeBlocks = (NE + 255) / 256;
  int spBlocks   = (NNODES * 64 + 255) / 256;
  int gaBlocks   = (NSLOTS * 16 + 255) / 256;
  int slBlocks   = (NSLOTS * 64 + 255) / 256;
  int mkBlocks   = (NSLOTS + 255) / 256;
  int lsBlocks   = (BATCH * 64 + 255) / 256;

  hipMemsetAsync(cnt, 0, (size_t)NNODES * 4, stream);
  hipMemsetAsync(flag, 0, NNODES, stream);
  hipMemsetAsync(accU, 0, accBytes, stream);

  conv_kernel<<<convBlocks, 256, 0, stream>>>(all_embed, xb0);
  hist_kernel<<<histBlocks, 256, 0, stream>>>(edge_row, cnt);
  scan1_kernel<<<NBLK1, 256, 0, stream>>>(cnt, rowptr, bsum);
  scan2_kernel<<<1, 1024, 0, stream>>>(bsum, NBLK1);
  scan3_kernel<<<(NNODES + 255) / 256, 256, 0, stream>>>(rowptr, bsum);
  seed_kernel<<<(NBUCK + 255) / 256, 256, 0, stream>>>(bcur, rowptr);
  binA_kernel<<<edgeBlocks, 256, 0, stream>>>(edge_row, edge_col, edge_val,
                                              bcur, binned);
  binB_kernel<<<NBUCK, 512, 0, stream>>>(binned, rowptr, ev);
  mark_kernel<<<mkBlocks, 256, 0, stream>>>(user, pos, neg, rowptr, ev, flag);

  // hop 0
  gather_acc_f32<<<gaBlocks, 256, 0, stream>>>(all_embed, accU, accP, accN,
                                               user, pos, neg);
  // hop 1 (all rows) — writes bufA, binned is dead by now
  spmm_pull_kernel<false><<<spBlocks, 256, 0, stream>>>(xb0, bufA, ev, rowptr,
                                                        flag);
  gather_acc_bf16<<<gaBlocks, 256, 0, stream>>>(bufA, accU, accP, accN,
                                                user, pos, neg);
  // hop 2 (flagged rows only)
  spmm_pull_kernel<true><<<spBlocks, 256, 0, stream>>>(bufA, bufB, ev, rowptr,
                                                       flag);
  gather_acc_bf16<<<gaBlocks, 256, 0, stream>>>(bufB, accU, accP, accN,
                                                user, pos, neg);
  // hop 3 (batch rows only)
  slot_pull_kernel<<<slBlocks, 256, 0, stream>>>(bufB, accU, accP, accN,
                                                 user, pos, neg, ev, rowptr);

  loss_kernel<<<lsBlocks, 256, 0, stream>>>(accU, accP, accN, all_embed,
                                            user, pos, neg, partial);
  finalize_kernel<<<1, 64, 0, stream>>>(partial, out);
}